// Round 2
// baseline (437.843 us; speedup 1.0000x reference)
//
#include <hip/hip_runtime.h>

#define NUM_REGIONS 116
#define EPS 1e-6f
#define GAMMA 1e-3f

// u32 LDS packing: count in bits [22,32), sum in bits [0,22) at 2^-14 fixed point.
// Per sub-table bin: ~6.6 mean elements (binomial(768, 1/116)), <<1023 count cap;
// sum cap 2^22/2^14 = 256 vs expected ~10. Huge margin.
#define SUM_SCALE 16384.0f
#define SUM_INV   (1.0f / 16384.0f)
#define CNT32_SHIFT 22
#define SUM32_MASK ((1u << CNT32_SHIFT) - 1u)

// u64 global packing: count in bits [40,64), sum (2^-14 fixed) in [0,40).
// Totals: count 12.58M < 2^24 = 16.8M; sum 12.58M*1.13*2^14 = 2.3e11 < 2^40 = 1.1e12.
#define CNT64_SHIFT 40
#define SUM64_MASK ((1ULL << CNT64_SHIFT) - 1ULL)

#define NSUB 8  // 2 parity sub-tables per wave x 4 waves

typedef unsigned long long u64;
typedef unsigned int u32;

__global__ __launch_bounds__(256) void region_fused_kernel(
    const float* __restrict__ real,
    const float* __restrict__ fake,
    const int*   __restrict__ rmap,
    u64* __restrict__ g_acc,   // [NUM_REGIONS], pre-zeroed
    u32* __restrict__ g_ctr,   // [1], pre-zeroed
    float* __restrict__ out,
    int n, int n4, int nblocks, float inv_n)
{
    // Sub-table stride = 116 words; 116 mod 32 = 20 => the 8 copies of a given
    // bin land in 8 distinct banks (k*20 mod 32 cycles through 8 values).
    __shared__ u32 s_acc[NSUB][NUM_REGIONS];
    __shared__ float s_red[3][128];
    __shared__ int s_last;

    const int tid = threadIdx.x;
    u32* tbl = s_acc[((tid >> 6) << 1) | (tid & 1)];

    for (int i = tid; i < NSUB * NUM_REGIONS; i += 256)
        (&s_acc[0][0])[i] = 0u;
    __syncthreads();

    const float4* real4 = (const float4*)real;
    const float4* fake4 = (const float4*)fake;
    const int4*   map4  = (const int4*)rmap;

    const int stride = nblocks * 256;
    for (int i = blockIdx.x * 256 + tid; i < n4; i += stride) {
        float4 a = real4[i];
        float4 b = fake4[i];
        int4   m = map4[i];
        u32 vx = (1u << CNT32_SHIFT) | (u32)(fabsf(a.x - b.x) * SUM_SCALE + 0.5f);
        u32 vy = (1u << CNT32_SHIFT) | (u32)(fabsf(a.y - b.y) * SUM_SCALE + 0.5f);
        u32 vz = (1u << CNT32_SHIFT) | (u32)(fabsf(a.z - b.z) * SUM_SCALE + 0.5f);
        u32 vw = (1u << CNT32_SHIFT) | (u32)(fabsf(a.w - b.w) * SUM_SCALE + 0.5f);
        atomicAdd(&tbl[m.x], vx);
        atomicAdd(&tbl[m.y], vy);
        atomicAdd(&tbl[m.z], vz);
        atomicAdd(&tbl[m.w], vw);
    }

    // Scalar tail (n not divisible by 4) — block 0.
    const int tail = n4 << 2;
    if (blockIdx.x == 0 && tid < (n - tail)) {
        int idx = tail + tid;
        u32 v = (1u << CNT32_SHIFT) |
                (u32)(fabsf(real[idx] - fake[idx]) * SUM_SCALE + 0.5f);
        atomicAdd(&tbl[rmap[idx]], v);
    }
    __syncthreads();

    // Merge 8 sub-tables -> one u64 global atomic per region per block.
    if (tid < NUM_REGIONS) {
        u64 sum = 0, cnt = 0;
#pragma unroll
        for (int k = 0; k < NSUB; ++k) {
            u32 v = s_acc[k][tid];
            sum += (u64)(v & SUM32_MASK);
            cnt += (u64)(v >> CNT32_SHIFT);
        }
        u64 packed = (cnt << CNT64_SHIFT) | sum;
        if (packed) atomicAdd(&g_acc[tid], packed);
    }
    __threadfence();   // drain this wave's global atomics before signaling
    __syncthreads();   // all waves' atomics drained before tid 0 signals

    if (tid == 0) {
        u32 prev = atomicAdd(g_ctr, 1u);
        s_last = (prev == (u32)(nblocks - 1)) ? 1 : 0;
    }
    __syncthreads();
    if (!s_last) return;

    // ---- Last block: finalize ----
    __threadfence();
    float mean = 0.f, ssum = 0.f;
    if (tid < NUM_REGIONS) {
        // atomic read-back => coherent value across XCDs
        u64 t = atomicAdd(&g_acc[tid], 0ULL);
        ssum = (float)(t & SUM64_MASK) * SUM_INV;
        float c = (float)(t >> CNT64_SHIFT);
        mean = ssum / (c + EPS);
    }
    if (tid < 128) {
        s_red[0][tid] = mean;          // for max
        s_red[1][tid] = ssum;          // for sum S_r
        s_red[2][tid] = ssum * mean;   // for sum S_r * mean_r
    }
    __syncthreads();
    if (tid < 64) {
        float mx = fmaxf(s_red[0][tid], s_red[0][tid + 64]);
        float a  = s_red[1][tid] + s_red[1][tid + 64];
        float b  = s_red[2][tid] + s_red[2][tid + 64];
#pragma unroll
        for (int off = 32; off > 0; off >>= 1) {
            mx = fmaxf(mx, __shfl_xor(mx, off));
            a += __shfl_xor(a, off);
            b += __shfl_xor(b, off);
        }
        if (tid == 0) {
            mx = fmaxf(mx, 0.0f);                 // jnp.maximum(max, 0.0)
            const float k = GAMMA / (mx + EPS);
            out[0] = (a + k * b) * inv_n;         // mean of w[region]*|real-fake|
        }
    }
}

extern "C" void kernel_launch(void* const* d_in, const int* in_sizes, int n_in,
                              void* d_out, int out_size, void* d_ws, size_t ws_size,
                              hipStream_t stream) {
    const float* real = (const float*)d_in[0];
    const float* fake = (const float*)d_in[1];
    const int*   rmap = (const int*)d_in[2];
    float* out = (float*)d_out;

    const int n  = in_sizes[0];
    const int n4 = n >> 2;

    u64* g_acc = (u64*)d_ws;
    u32* g_ctr = (u32*)((char*)d_ws + NUM_REGIONS * sizeof(u64));
    hipMemsetAsync(d_ws, 0, NUM_REGIONS * sizeof(u64) + sizeof(u32), stream);

    int nblocks = (n4 + 255) / 256;
    if (nblocks > 2048) nblocks = 2048;
    if (nblocks < 1) nblocks = 1;

    region_fused_kernel<<<nblocks, 256, 0, stream>>>(
        real, fake, rmap, g_acc, g_ctr, out, n, n4, nblocks, 1.0f / (float)n);
}

// Round 3
// 187.540 us; speedup vs baseline: 2.3347x; 2.3347x over previous
//
#include <hip/hip_runtime.h>

#define NUM_REGIONS 116
#define EPS 1e-6f
#define GAMMA 1e-3f

// Fixed-point packing: low 40 bits = sum * 2^20, high 24 bits = count.
// Worst-case per-region total sum ~ 1.3e11 (~2^37) << 2^40; count ~12.6M < 2^24.
#define FIX_SCALE 1048576.0f
#define FIX_INV   (1.0f / 1048576.0f)
#define CNT_SHIFT 40
#define SUM_MASK  ((1ULL << CNT_SHIFT) - 1ULL)

// Unroll: each thread handles 4 float4-groups (16 elements), block-strided.
#define UNROLL 4
#define GROUPS_PER_BLOCK (256 * UNROLL)

typedef unsigned long long u64;
typedef unsigned int u32;

__global__ __launch_bounds__(256) void region_accum_kernel(
    const float* __restrict__ real,
    const float* __restrict__ fake,
    const int*   __restrict__ rmap,
    u64* __restrict__ g_acc,
    int n, int n4)
{
    __shared__ u64 s_acc[4][NUM_REGIONS];
    const int tid = threadIdx.x;
    u64* tbl = s_acc[tid >> 6];   // wave-private table (round-1 scheme, verified)

    for (int i = tid; i < 4 * NUM_REGIONS; i += 256)
        (&s_acc[0][0])[i] = 0ULL;
    __syncthreads();

    const float4* real4 = (const float4*)real;
    const float4* fake4 = (const float4*)fake;
    const int4*   map4  = (const int4*)rmap;

    const int base = blockIdx.x * GROUPS_PER_BLOCK + tid;

    if (base + 256 * (UNROLL - 1) < n4) {
        // Fast path: batch all 12 independent dwordx4 loads before any LDS op
        // (maximize outstanding memory requests -> hide ~900cyc HBM latency).
        float4 a0 = real4[base];
        float4 a1 = real4[base + 256];
        float4 a2 = real4[base + 512];
        float4 a3 = real4[base + 768];
        float4 b0 = fake4[base];
        float4 b1 = fake4[base + 256];
        float4 b2 = fake4[base + 512];
        float4 b3 = fake4[base + 768];
        int4   m0 = map4[base];
        int4   m1 = map4[base + 256];
        int4   m2 = map4[base + 512];
        int4   m3 = map4[base + 768];

#define ACC1(av, bv, mv) \
        atomicAdd(&tbl[mv], (1ULL << CNT_SHIFT) | \
            (u64)(unsigned)(fabsf((av) - (bv)) * FIX_SCALE + 0.5f))
#define ACC4(a, b, m) \
        ACC1(a.x, b.x, m.x); ACC1(a.y, b.y, m.y); \
        ACC1(a.z, b.z, m.z); ACC1(a.w, b.w, m.w)

        ACC4(a0, b0, m0);
        ACC4(a1, b1, m1);
        ACC4(a2, b2, m2);
        ACC4(a3, b3, m3);
    } else {
        // Guarded slow path (partial last block).
#pragma unroll
        for (int k = 0; k < UNROLL; ++k) {
            int i = base + 256 * k;
            if (i < n4) {
                float4 a = real4[i];
                float4 b = fake4[i];
                int4   m = map4[i];
                ACC4(a, b, m);
            }
        }
    }

    // Scalar tail (n not divisible by 4) — block 0.
    const int tail = n4 << 2;
    if (blockIdx.x == 0 && tid < (n - tail)) {
        int idx = tail + tid;
        ACC1(real[idx], fake[idx], rmap[idx]);
    }
    __syncthreads();

    // Merge 4 wave copies, one global u64 atomic per region per block.
    for (int r = tid; r < NUM_REGIONS; r += 256) {
        u64 t = s_acc[0][r] + s_acc[1][r] + s_acc[2][r] + s_acc[3][r];
        if (t) atomicAdd(&g_acc[r], t);
    }
}

__global__ __launch_bounds__(64) void region_finalize_kernel(
    const u64* __restrict__ g_acc,
    float* __restrict__ out,
    float inv_n)
{
    const int lane = threadIdx.x;  // one wave
    u64 tA = g_acc[lane];
    float sA = (float)(tA & SUM_MASK) * FIX_INV;
    float cA = (float)(tA >> CNT_SHIFT);
    float mA = sA / (cA + EPS);

    float sB = 0.0f, mB = 0.0f;
    if (lane + 64 < NUM_REGIONS) {
        u64 tB = g_acc[lane + 64];
        sB = (float)(tB & SUM_MASK) * FIX_INV;
        float cB = (float)(tB >> CNT_SHIFT);
        mB = sB / (cB + EPS);
    }

    float mx = fmaxf(mA, mB);
#pragma unroll
    for (int off = 32; off > 0; off >>= 1)
        mx = fmaxf(mx, __shfl_xor(mx, off));
    mx = fmaxf(mx, 0.0f);  // jnp.maximum(max, 0.0)

    const float k = GAMMA / (mx + EPS);
    float part = sA * (1.0f + mA * k) + sB * (1.0f + mB * k);
#pragma unroll
    for (int off = 32; off > 0; off >>= 1)
        part += __shfl_xor(part, off);

    if (lane == 0)
        out[0] = part * inv_n;
}

extern "C" void kernel_launch(void* const* d_in, const int* in_sizes, int n_in,
                              void* d_out, int out_size, void* d_ws, size_t ws_size,
                              hipStream_t stream) {
    const float* real = (const float*)d_in[0];
    const float* fake = (const float*)d_in[1];
    const int*   rmap = (const int*)d_in[2];
    float* out = (float*)d_out;

    const int n  = in_sizes[0];
    const int n4 = n >> 2;

    u64* g_acc = (u64*)d_ws;
    hipMemsetAsync(d_ws, 0, NUM_REGIONS * sizeof(u64), stream);

    int blocks = (n4 + GROUPS_PER_BLOCK - 1) / GROUPS_PER_BLOCK;
    if (blocks < 1) blocks = 1;

    region_accum_kernel<<<blocks, 256, 0, stream>>>(real, fake, rmap, g_acc, n, n4);
    region_finalize_kernel<<<1, 64, 0, stream>>>(g_acc, out, 1.0f / (float)n);
}

// Round 4
// 183.083 us; speedup vs baseline: 2.3915x; 1.0243x over previous
//
#include <hip/hip_runtime.h>

#define NUM_REGIONS 116
#define EPS 1e-6f
#define GAMMA 1e-3f

// u32 LDS packing: count in bits [21,32) (cap 2047), sum in bits [0,21) at
// 2^-11 fixed point (cap 1024.0). Per wave (<=1536 elements over 116 bins):
// expected per-bin count ~13, max ~45; per-bin sum max ~60 -> huge margin.
// Quantization: +-2^-12 per element, RMS over 108k elems/region ~0.05 on
// region sums of ~1.2e5 -> relative 4e-7. Far under threshold.
#define SUM_SCALE 2048.0f
#define CNT32_SHIFT 21
#define SUM32_MASK ((1u << CNT32_SHIFT) - 1u)

// u64 global packing: count in [40,64), sum (2^-11 units) in [0,40).
// Totals: count 12.6M < 2^24; sum 12.6M*1.13*2048 = 2.9e10 < 2^40.
#define FIX_INV   (1.0f / 2048.0f)
#define CNT_SHIFT 40
#define SUM_MASK  ((1ULL << CNT_SHIFT) - 1ULL)

typedef unsigned long long u64;
typedef unsigned int u32;

__global__ __launch_bounds__(256) void region_accum_kernel(
    const float* __restrict__ real,
    const float* __restrict__ fake,
    const int*   __restrict__ rmap,
    u64* __restrict__ g_acc,
    int n, int n4)
{
    // Per-wave privatized u32 histograms (round-1 structure, width halved).
    __shared__ u32 s_acc[4][NUM_REGIONS];
    const int tid = threadIdx.x;
    u32* tbl = s_acc[tid >> 6];

    for (int i = tid; i < 4 * NUM_REGIONS; i += 256)
        (&s_acc[0][0])[i] = 0u;
    __syncthreads();

    const float4* real4 = (const float4*)real;
    const float4* fake4 = (const float4*)fake;
    const int4*   map4  = (const int4*)rmap;

    const int stride = gridDim.x * 256;
    for (int i = blockIdx.x * 256 + tid; i < n4; i += stride) {
        float4 a = real4[i];
        float4 b = fake4[i];
        int4   m = map4[i];
        u32 vx = (1u << CNT32_SHIFT) | (u32)(fabsf(a.x - b.x) * SUM_SCALE + 0.5f);
        u32 vy = (1u << CNT32_SHIFT) | (u32)(fabsf(a.y - b.y) * SUM_SCALE + 0.5f);
        u32 vz = (1u << CNT32_SHIFT) | (u32)(fabsf(a.z - b.z) * SUM_SCALE + 0.5f);
        u32 vw = (1u << CNT32_SHIFT) | (u32)(fabsf(a.w - b.w) * SUM_SCALE + 0.5f);
        atomicAdd(&tbl[m.x], vx);
        atomicAdd(&tbl[m.y], vy);
        atomicAdd(&tbl[m.z], vz);
        atomicAdd(&tbl[m.w], vw);
    }

    // Scalar tail (n not divisible by 4) — block 0.
    const int tail = n4 << 2;
    if (blockIdx.x == 0 && tid < (n - tail)) {
        int idx = tail + tid;
        u32 v = (1u << CNT32_SHIFT) |
                (u32)(fabsf(real[idx] - fake[idx]) * SUM_SCALE + 0.5f);
        atomicAdd(&tbl[rmap[idx]], v);
    }
    __syncthreads();

    // Merge 4 wave copies, one global u64 atomic per region per block.
    for (int r = tid; r < NUM_REGIONS; r += 256) {
        u64 sum = 0, cnt = 0;
#pragma unroll
        for (int k = 0; k < 4; ++k) {
            u32 v = s_acc[k][r];
            sum += (u64)(v & SUM32_MASK);
            cnt += (u64)(v >> CNT32_SHIFT);
        }
        u64 packed = (cnt << CNT_SHIFT) | sum;
        if (packed) atomicAdd(&g_acc[r], packed);
    }
}

__global__ __launch_bounds__(64) void region_finalize_kernel(
    const u64* __restrict__ g_acc,
    float* __restrict__ out,
    float inv_n)
{
    const int lane = threadIdx.x;  // one wave
    u64 tA = g_acc[lane];
    float sA = (float)(tA & SUM_MASK) * FIX_INV;
    float cA = (float)(tA >> CNT_SHIFT);
    float mA = sA / (cA + EPS);

    float sB = 0.0f, mB = 0.0f;
    if (lane + 64 < NUM_REGIONS) {
        u64 tB = g_acc[lane + 64];
        sB = (float)(tB & SUM_MASK) * FIX_INV;
        float cB = (float)(tB >> CNT_SHIFT);
        mB = sB / (cB + EPS);
    }

    float mx = fmaxf(mA, mB);
#pragma unroll
    for (int off = 32; off > 0; off >>= 1)
        mx = fmaxf(mx, __shfl_xor(mx, off));
    mx = fmaxf(mx, 0.0f);  // jnp.maximum(max, 0.0)

    const float k = GAMMA / (mx + EPS);
    float part = sA * (1.0f + mA * k) + sB * (1.0f + mB * k);
#pragma unroll
    for (int off = 32; off > 0; off >>= 1)
        part += __shfl_xor(part, off);

    if (lane == 0)
        out[0] = part * inv_n;
}

extern "C" void kernel_launch(void* const* d_in, const int* in_sizes, int n_in,
                              void* d_out, int out_size, void* d_ws, size_t ws_size,
                              hipStream_t stream) {
    const float* real = (const float*)d_in[0];
    const float* fake = (const float*)d_in[1];
    const int*   rmap = (const int*)d_in[2];
    float* out = (float*)d_out;

    const int n  = in_sizes[0];
    const int n4 = n >> 2;

    u64* g_acc = (u64*)d_ws;
    hipMemsetAsync(d_ws, 0, NUM_REGIONS * sizeof(u64), stream);

    int blocks = (n4 + 255) / 256;
    if (blocks > 2048) blocks = 2048;
    if (blocks < 1) blocks = 1;

    region_accum_kernel<<<blocks, 256, 0, stream>>>(real, fake, rmap, g_acc, n, n4);
    region_finalize_kernel<<<1, 64, 0, stream>>>(g_acc, out, 1.0f / (float)n);
}